// Round 1
// baseline (418.350 us; speedup 1.0000x reference)
//
#include <hip/hip_runtime.h>

#define LOG_2PI_F 1.8378770664093453f

constexpr int BC = 1024;   // B_CAPS
constexpr int CC = 16;     // C_CAPS
constexpr int PV = 16;     // P_VEC
constexpr int LV = 64;     // L_VEC
constexpr int BB = 4;      // BATCH
constexpr int NROW = 64;   // BATCH * WIN * WIN rows per capsule
constexpr int CH = (PV + 1) * BC;  // 17408 channels in x
constexpr int NSLAB = 32;
constexpr int SLAB = BB * CC * LV;          // 4096
constexpr int SLABTOT = 2 * SLAB + BB * CC; // 8256: S1 | S2 | Sr

__device__ __forceinline__ float wave_sum(float v) {
#pragma unroll
  for (int m = 1; m < 64; m <<= 1) v += __shfl_xor(v, m, 64);
  return v;
}

// One block per input capsule i. Thread t owns 4 (c,l) columns: cl = t + 256j.
// Within wave w, c = w + 4j and lane == l. PASS0: uniform R. PASS1: softmax(R) from mu/T.
template <int PASS>
__global__ __launch_bounds__(256, 2) void em_sweep(
    const float* __restrict__ x, const float* __restrict__ W,
    const float* __restrict__ mu, const float* __restrict__ T,
    float* __restrict__ Spart) {
  const int i = blockIdx.x;
  const int t = threadIdx.x;
  const int w = t >> 6;
  const int lane = t & 63;

  float* S1p = Spart + (size_t)(blockIdx.x & (NSLAB - 1)) * SLABTOT;
  float* S2p = S1p + SLAB;
  float* Srp = S1p + 2 * SLAB;

  __shared__ float pose_s[NROW][PV];
  __shared__ float act_s[NROW];
  __shared__ float T_s[BB * CC];
  __shared__ float sc_s[4][CC];
  __shared__ float rh_s[4][CC];

  // W_i columns -> registers (coalesced dwordx4; W has no cross-block reuse)
  float Wr[4][16];
#pragma unroll
  for (int j = 0; j < 4; j++) {
    const int cl = t + 256 * j;
    const int c = cl >> 6, l = cl & 63;
    const float4* wp =
        reinterpret_cast<const float4*>(W + ((size_t)(c * BC + i) * LV + l) * PV);
#pragma unroll
    for (int q = 0; q < 4; q++) {
      const float4 v = wp[q];
      Wr[j][4 * q + 0] = v.x; Wr[j][4 * q + 1] = v.y;
      Wr[j][4 * q + 2] = v.z; Wr[j][4 * q + 3] = v.w;
    }
  }

  // stage pose rows (b*16+xy, p) and activations for this capsule
  for (int idx = t; idx < BB * PV * 16; idx += 256) {
    const int b = idx >> 8, p = (idx >> 4) & 15, xy = idx & 15;
    pose_s[b * 16 + xy][p] = x[(size_t)(b * CH + p * BC + i) * 16 + xy];
  }
  if (t < NROW) {
    const int b = t >> 4, xy = t & 15;
    act_s[t] = x[(size_t)(b * CH + PV * BC + i) * 16 + xy];
    if (PASS == 1) T_s[t] = T[t];
  }

  float mur[4][4];
  if (PASS == 1) {
#pragma unroll
    for (int j = 0; j < 4; j++) {
      const int cl = t + 256 * j;
      const int c = cl >> 6, l = cl & 63;
#pragma unroll
      for (int b = 0; b < 4; b++) mur[j][b] = mu[(b * CC + c) * LV + l];
    }
  }
  __syncthreads();

  float S1a[4][4] = {};
  float S2a[4][4] = {};
  float sr_acc[4] = {};

#pragma unroll
  for (int b = 0; b < 4; b++) {
    for (int r0 = b * 16; r0 < (b + 1) * 16; r0 += 4) {
      // votes for 4 rows x 4 owned columns
      float V[4][4];  // [rr][j]
#pragma unroll
      for (int rr = 0; rr < 4; rr++) {
        float pr[16];
#pragma unroll
        for (int p = 0; p < 16; p++) pr[p] = pose_s[r0 + rr][p];
#pragma unroll
        for (int j = 0; j < 4; j++) {
          float v = 0.f;
#pragma unroll
          for (int p = 0; p < 16; p++) v = fmaf(Wr[j][p], pr[p], v);
          V[rr][j] = v;
        }
      }

      if (PASS == 1) {
        // score_c = T[b,c] - sum_l (V-mu)^2 ; lane == l so wave-reduce over l
#pragma unroll
        for (int rr = 0; rr < 4; rr++)
#pragma unroll
          for (int j = 0; j < 4; j++) {
            const float d = V[rr][j] - mur[j][b];
            const float s = wave_sum(d * d);
            if (lane == 0) sc_s[rr][w + 4 * j] = s;
          }
        __syncthreads();
        if (t < 64) {  // softmax over c: lane = rr*16 + c
          const int rr = t >> 4, c = t & 15;
          float s = T_s[b * CC + c] - sc_s[rr][c];
          float m = s;
#pragma unroll
          for (int k = 1; k < 16; k <<= 1) m = fmaxf(m, __shfl_xor(m, k, 64));
          const float e = __expf(s - m);
          float den = e;
#pragma unroll
          for (int k = 1; k < 16; k <<= 1) den += __shfl_xor(den, k, 64);
          const float rh = fmaxf((e / den) * act_s[r0 + rr], 0.01f);
          rh_s[rr][c] = rh;
          sr_acc[b] += rh;
        }
        __syncthreads();
#pragma unroll
        for (int rr = 0; rr < 4; rr++)
#pragma unroll
          for (int j = 0; j < 4; j++) {
            const float rh = rh_s[rr][w + 4 * j];
            S1a[j][b] = fmaf(rh, V[rr][j], S1a[j][b]);
            S2a[j][b] = fmaf(rh * V[rr][j], V[rr][j], S2a[j][b]);
          }
      } else {
#pragma unroll
        for (int rr = 0; rr < 4; rr++) {
          const float rh = fmaxf(act_s[r0 + rr] * 0.0625f, 0.01f);
          if (t == 0) sr_acc[b] += rh;
#pragma unroll
          for (int j = 0; j < 4; j++) {
            S1a[j][b] = fmaf(rh, V[rr][j], S1a[j][b]);
            S2a[j][b] = fmaf(rh * V[rr][j], V[rr][j], S2a[j][b]);
          }
        }
      }
    }
  }

  // slab-partial accumulation (coalesced per-wave atomics, 32-way de-contended)
#pragma unroll
  for (int j = 0; j < 4; j++) {
    const int cl = t + 256 * j;
    const int c = cl >> 6, l = cl & 63;
#pragma unroll
    for (int b = 0; b < 4; b++) {
      atomicAdd(&S1p[(b * CC + c) * LV + l], S1a[j][b]);
      atomicAdd(&S2p[(b * CC + c) * LV + l], S2a[j][b]);
    }
  }
  if (PASS == 1) {
    if (t < 64) {
      const int c = t & 15;
#pragma unroll
      for (int b = 0; b < 4; b++) atomicAdd(&Srp[b * CC + c], sr_acc[b]);
    }
  } else {
    if (t == 0) {
#pragma unroll
      for (int b = 0; b < 4; b++)
        for (int c = 0; c < CC; c++) atomicAdd(&Srp[b * CC + c], sr_acc[b]);
    }
  }
}

__global__ void reduce_slabs(const float* __restrict__ Spart, float* __restrict__ Sred) {
  const int t = blockIdx.x * 256 + threadIdx.x;
  if (t >= SLABTOT) return;
  float a = 0.f;
#pragma unroll 4
  for (int s = 0; s < NSLAB; s++) a += Spart[(size_t)s * SLABTOT + t];
  Sred[t] = a;
}

// From reduced stats: mu, sigma, a_c. FINAL=0 -> write mu + T for sweep 2.
// FINAL=1 -> write output (mus then acts).
template <int FINAL>
__global__ void stats_post(const float* __restrict__ Sred,
                           const float* __restrict__ beta_v,
                           const float* __restrict__ beta_a,
                           const float* __restrict__ lam,
                           float* __restrict__ mu_out, float* __restrict__ T_out,
                           float* __restrict__ out) {
  const int t = threadIdx.x;
  if (t >= 64) return;
  const int b = t >> 4, c = t & 15;
  const float* S1 = Sred;
  const float* S2 = Sred + SLAB;
  const float sr = Sred[2 * SLAB + b * CC + c];
  const float inv = 1.f / sr;
  const float bv = beta_v[0];
  float csum = 0.f, lsum = 0.f;
  for (int l = 0; l < LV; l++) {
    const int idx = (b * CC + c) * LV + l;
    const float m = S1[idx] * inv;
    float s2 = S2[idx] * inv - m * m;  // == sum r (V-mu)^2 / sum r
    s2 = fmaxf(s2, 0.01f);
    const float ls = logf(s2);
    csum += bv + ls;
    lsum += ls;
    if (FINAL) out[(size_t)b * 1040 + c * LV + l] = m;
    else mu_out[idx] = m;
  }
  const float z = lam[0] * (beta_a[c] - csum * sr);
  const float ac = 1.f / (1.f + expf(-z));
  if (FINAL) out[(size_t)b * 1040 + 1024 + c] = ac;
  else T_out[b * CC + c] = logf(ac) - 0.5f * (64.f * LOG_2PI_F + lsum);
}

extern "C" void kernel_launch(void* const* d_in, const int* in_sizes, int n_in,
                              void* d_out, int out_size, void* d_ws, size_t ws_size,
                              hipStream_t stream) {
  const float* x = (const float*)d_in[0];
  const float* W = (const float*)d_in[1];
  const float* beta_v = (const float*)d_in[2];
  const float* beta_a = (const float*)d_in[3];
  const float* lam = (const float*)d_in[4];
  float* out = (float*)d_out;

  float* Spart = (float*)d_ws;                        // 32 * 8256 floats
  float* Sred = Spart + (size_t)NSLAB * SLABTOT;      // 8256
  float* muW = Sred + SLABTOT;                        // 4096
  float* Tw = muW + SLAB;                             // 64

  hipMemsetAsync(Spart, 0, (size_t)NSLAB * SLABTOT * sizeof(float), stream);
  em_sweep<0><<<dim3(BC), dim3(256), 0, stream>>>(x, W, nullptr, nullptr, Spart);
  reduce_slabs<<<dim3((SLABTOT + 255) / 256), dim3(256), 0, stream>>>(Spart, Sred);
  stats_post<0><<<dim3(1), dim3(64), 0, stream>>>(Sred, beta_v, beta_a, lam, muW, Tw, nullptr);

  hipMemsetAsync(Spart, 0, (size_t)NSLAB * SLABTOT * sizeof(float), stream);
  em_sweep<1><<<dim3(BC), dim3(256), 0, stream>>>(x, W, muW, Tw, Spart);
  reduce_slabs<<<dim3((SLABTOT + 255) / 256), dim3(256), 0, stream>>>(Spart, Sred);
  stats_post<1><<<dim3(1), dim3(64), 0, stream>>>(Sred, beta_v, beta_a, lam, nullptr, nullptr, out);
}

// Round 2
// 208.830 us; speedup vs baseline: 2.0033x; 2.0033x over previous
//
#include <hip/hip_runtime.h>

#define LOG_2PI_F 1.8378770664093453f

constexpr int BC = 1024, CC = 16, PV = 16, LV = 64, BB = 4, NROW = 64;
constexpr int CH = (PV + 1) * BC;
constexpr int SLAB = BB * CC * LV;           // 4096
constexpr int SLABTOT = 2 * SLAB + BB * CC;  // 8256
constexpr int NSLAB_SM = 32;

// Thread t owns (c = t>>4, l = 4*(t&15)..+3). Lanes 16k..16k+15 share c.
// PASS0: uniform R (no scores). PASS1: softmax(R) from mu/T.
// STORE=1: private slab per block, plain float4 stores. STORE=0: 32 shared slabs, atomics.
template <int PASS, int STORE>
__global__ __launch_bounds__(256, 2) void em_sweep(
    const float* __restrict__ x, const float* __restrict__ W,
    const float* __restrict__ mu, const float* __restrict__ T,
    float* __restrict__ Spart, int nslab) {
  const int i = blockIdx.x;
  const int t = threadIdx.x;
  const int c = t >> 4;
  const int l0 = 4 * (t & 15);

  float* S1p = Spart + (size_t)(blockIdx.x % nslab) * SLABTOT;
  float* S2p = S1p + SLAB;
  float* Srp = S1p + 2 * SLAB;

  __shared__ float pose_s[NROW][PV];
  __shared__ float act_s[NROW];
  __shared__ float T_s[BB * CC];
  __shared__ float sc_s[NROW][17];  // pad 17: bank = (17r+c)%32, conflict-free
  __shared__ float rh_s[NROW][17];
  __shared__ float sr_s[BB * CC];

  // W[c][i][l0..l0+3][0..15] -> regs; wave reads contiguous 16KB per c-group
  float Wr[4][16];
  {
    const float4* wp =
        reinterpret_cast<const float4*>(W + (((size_t)c * BC + i) * LV + l0) * PV);
#pragma unroll
    for (int ll = 0; ll < 4; ll++)
#pragma unroll
      for (int q = 0; q < 4; q++) {
        const float4 v = wp[ll * 4 + q];
        Wr[ll][4 * q] = v.x; Wr[ll][4 * q + 1] = v.y;
        Wr[ll][4 * q + 2] = v.z; Wr[ll][4 * q + 3] = v.w;
      }
  }

  for (int idx = t; idx < BB * PV * 16; idx += 256) {
    const int b = idx >> 8, p = (idx >> 4) & 15, xy = idx & 15;
    pose_s[b * 16 + xy][p] = x[((size_t)(b * CH + p * BC + i)) * 16 + xy];
  }
  if (t < NROW) {
    const int b = t >> 4, xy = t & 15;
    act_s[t] = x[((size_t)(b * CH + PV * BC + i)) * 16 + xy];
    if (PASS == 1) { T_s[t] = T[t]; sr_s[t] = 0.f; }
  }

  float mur[4][4];  // [b][ll]
  if (PASS == 1) {
#pragma unroll
    for (int b = 0; b < 4; b++) {
      const float4 v = *reinterpret_cast<const float4*>(mu + (b * CC + c) * LV + l0);
      mur[b][0] = v.x; mur[b][1] = v.y; mur[b][2] = v.z; mur[b][3] = v.w;
    }
  }
  __syncthreads();

  if (PASS == 1) {
    // ---- phase A: score(r,c) = sum_l (V - mu)^2, no barriers inside ----
#pragma unroll
    for (int b = 0; b < 4; b++) {
      for (int xy = 0; xy < 16; xy++) {
        const int r = b * 16 + xy;
        float pr[16];
        const float4* pp = reinterpret_cast<const float4*>(&pose_s[r][0]);
#pragma unroll
        for (int q = 0; q < 4; q++) {
          const float4 v = pp[q];
          pr[4 * q] = v.x; pr[4 * q + 1] = v.y; pr[4 * q + 2] = v.z; pr[4 * q + 3] = v.w;
        }
        float sc = 0.f;
#pragma unroll
        for (int ll = 0; ll < 4; ll++) {
          float v = 0.f;
#pragma unroll
          for (int p = 0; p < 16; p++) v = fmaf(Wr[ll][p], pr[p], v);
          const float d = v - mur[b][ll];
          sc = fmaf(d, d, sc);
        }
#pragma unroll
        for (int m = 1; m < 16; m <<= 1) sc += __shfl_xor(sc, m, 64);
        if ((t & 15) == 0) sc_s[r][c] = sc;
      }
    }
    __syncthreads();
    // ---- softmax over c, all 256 threads (4x redundant over rows, no shfl) ----
    {
      const int r = t & 63, cq = t >> 6, b = r >> 4;
      float s[16];
#pragma unroll
      for (int cc = 0; cc < 16; cc++) s[cc] = T_s[b * CC + cc] - sc_s[r][cc];
      float m = s[0];
#pragma unroll
      for (int cc = 1; cc < 16; cc++) m = fmaxf(m, s[cc]);
      float den = 0.f;
#pragma unroll
      for (int cc = 0; cc < 16; cc++) { s[cc] = __expf(s[cc] - m); den += s[cc]; }
      const float a = act_s[r] / den;
#pragma unroll
      for (int k = 0; k < 4; k++) {
        const int cc = 4 * cq + k;
        const float rh = fmaxf(s[cc] * a, 0.01f);
        rh_s[r][cc] = rh;
        atomicAdd(&sr_s[b * CC + cc], rh);  // LDS atomic, 16-way, cheap
      }
    }
    __syncthreads();
  }

  // ---- phase B: accumulate S1/S2 in registers (statically indexed) ----
  float S1a[4][4] = {}, S2a[4][4] = {};  // [b][ll]
#pragma unroll
  for (int b = 0; b < 4; b++) {
    for (int xy = 0; xy < 16; xy++) {
      const int r = b * 16 + xy;
      float pr[16];
      const float4* pp = reinterpret_cast<const float4*>(&pose_s[r][0]);
#pragma unroll
      for (int q = 0; q < 4; q++) {
        const float4 v = pp[q];
        pr[4 * q] = v.x; pr[4 * q + 1] = v.y; pr[4 * q + 2] = v.z; pr[4 * q + 3] = v.w;
      }
      const float rh = (PASS == 1) ? rh_s[r][c] : fmaxf(act_s[r] * 0.0625f, 0.01f);
#pragma unroll
      for (int ll = 0; ll < 4; ll++) {
        float v = 0.f;
#pragma unroll
        for (int p = 0; p < 16; p++) v = fmaf(Wr[ll][p], pr[p], v);
        S1a[b][ll] = fmaf(rh, v, S1a[b][ll]);
        S2a[b][ll] = fmaf(rh * v, v, S2a[b][ll]);
      }
    }
  }

  if (STORE) {
    // wave-contiguous float4 stores: addr = b*1024 + 4t
#pragma unroll
    for (int b = 0; b < 4; b++) {
      *reinterpret_cast<float4*>(S1p + (b * CC + c) * LV + l0) =
          make_float4(S1a[b][0], S1a[b][1], S1a[b][2], S1a[b][3]);
      *reinterpret_cast<float4*>(S2p + (b * CC + c) * LV + l0) =
          make_float4(S2a[b][0], S2a[b][1], S2a[b][2], S2a[b][3]);
    }
  } else {
#pragma unroll
    for (int b = 0; b < 4; b++)
#pragma unroll
      for (int ll = 0; ll < 4; ll++) {
        atomicAdd(&S1p[(b * CC + c) * LV + l0 + ll], S1a[b][ll]);
        atomicAdd(&S2p[(b * CC + c) * LV + l0 + ll], S2a[b][ll]);
      }
  }
  if (PASS == 1) {
    if (t < 64) { if (STORE) Srp[t] = sr_s[t]; else atomicAdd(&Srp[t], sr_s[t]); }
  } else {
    if (t < 64) {
      const int b = t >> 4;
      float s = 0.f;
#pragma unroll
      for (int xy = 0; xy < 16; xy++) s += fmaxf(act_s[b * 16 + xy] * 0.0625f, 0.01f);
      if (STORE) Srp[t] = s; else atomicAdd(&Srp[t], s);
    }
  }
}

// 2D tree reduce over slabs: grid.x covers SLABTOT, grid.y covers slab chunks.
__global__ void reduce_slabs(const float* __restrict__ Spart, float* __restrict__ Sred,
                             int nslab, int chunk) {
  const int idx = blockIdx.x * 256 + threadIdx.x;
  if (idx >= SLABTOT) return;
  const int s0 = blockIdx.y * chunk;
  const int s1 = min(s0 + chunk, nslab);
  float a = 0.f;
#pragma unroll 8
  for (int s = s0; s < s1; s++) a += Spart[(size_t)s * SLABTOT + idx];
  atomicAdd(&Sred[idx], a);
}

template <int FINAL>
__global__ void stats_post(const float* __restrict__ Sred,
                           const float* __restrict__ beta_v,
                           const float* __restrict__ beta_a,
                           const float* __restrict__ lam,
                           float* __restrict__ mu_out, float* __restrict__ T_out,
                           float* __restrict__ out) {
  const int t = threadIdx.x;
  if (t >= 64) return;
  const int b = t >> 4, c = t & 15;
  const float* S1 = Sred;
  const float* S2 = Sred + SLAB;
  const float sr = Sred[2 * SLAB + b * CC + c];
  const float inv = 1.f / sr;
  const float bv = beta_v[0];
  float csum = 0.f, lsum = 0.f;
  for (int l = 0; l < LV; l++) {
    const int idx = (b * CC + c) * LV + l;
    const float m = S1[idx] * inv;
    float s2 = S2[idx] * inv - m * m;  // == sum r (V-mu)^2 / sum r
    s2 = fmaxf(s2, 0.01f);
    const float ls = logf(s2);
    csum += bv + ls;
    lsum += ls;
    if (FINAL) out[(size_t)b * 1040 + c * LV + l] = m;
    else mu_out[idx] = m;
  }
  const float z = lam[0] * (beta_a[c] - csum * sr);
  const float ac = 1.f / (1.f + expf(-z));
  if (FINAL) out[(size_t)b * 1040 + 1024 + c] = ac;
  else T_out[b * CC + c] = logf(ac) - 0.5f * (64.f * LOG_2PI_F + lsum);
}

extern "C" void kernel_launch(void* const* d_in, const int* in_sizes, int n_in,
                              void* d_out, int out_size, void* d_ws, size_t ws_size,
                              hipStream_t stream) {
  const float* x = (const float*)d_in[0];
  const float* W = (const float*)d_in[1];
  const float* beta_v = (const float*)d_in[2];
  const float* beta_a = (const float*)d_in[3];
  const float* lam = (const float*)d_in[4];
  float* out = (float*)d_out;

  const size_t need =
      ((size_t)BC * SLABTOT + SLABTOT + SLAB + 64) * sizeof(float);
  const int nslab = (ws_size >= need) ? BC : NSLAB_SM;
  const bool store = (nslab == BC);

  float* Spart = (float*)d_ws;
  float* Sred = Spart + (size_t)nslab * SLABTOT;
  float* muW = Sred + SLABTOT;
  float* Tw = muW + SLAB;

  const int chunk = 32;
  const dim3 rgrid((SLABTOT + 255) / 256, (nslab + chunk - 1) / chunk);

  // ---- pass 0 ----
  if (!store) hipMemsetAsync(Spart, 0, (size_t)nslab * SLABTOT * sizeof(float), stream);
  hipMemsetAsync(Sred, 0, SLABTOT * sizeof(float), stream);
  if (store) em_sweep<0, 1><<<dim3(BC), dim3(256), 0, stream>>>(x, W, nullptr, nullptr, Spart, nslab);
  else       em_sweep<0, 0><<<dim3(BC), dim3(256), 0, stream>>>(x, W, nullptr, nullptr, Spart, nslab);
  reduce_slabs<<<rgrid, dim3(256), 0, stream>>>(Spart, Sred, nslab, chunk);
  stats_post<0><<<dim3(1), dim3(64), 0, stream>>>(Sred, beta_v, beta_a, lam, muW, Tw, nullptr);

  // ---- pass 1 ----
  if (!store) hipMemsetAsync(Spart, 0, (size_t)nslab * SLABTOT * sizeof(float), stream);
  hipMemsetAsync(Sred, 0, SLABTOT * sizeof(float), stream);
  if (store) em_sweep<1, 1><<<dim3(BC), dim3(256), 0, stream>>>(x, W, muW, Tw, Spart, nslab);
  else       em_sweep<1, 0><<<dim3(BC), dim3(256), 0, stream>>>(x, W, muW, Tw, Spart, nslab);
  reduce_slabs<<<rgrid, dim3(256), 0, stream>>>(Spart, Sred, nslab, chunk);
  stats_post<1><<<dim3(1), dim3(64), 0, stream>>>(Sred, beta_v, beta_a, lam, nullptr, nullptr, out);
}

// Round 3
// 140.583 us; speedup vs baseline: 2.9758x; 1.4855x over previous
//
#include <hip/hip_runtime.h>

#define LOG_2PI_F 1.8378770664093453f

constexpr int BC = 1024, CC = 16, PV = 16, LV = 64, BB = 4, NROW = 64;
constexpr int CH = (PV + 1) * BC;
constexpr int SLAB = BB * CC * LV;           // 4096
constexpr int SLABTOT = 2 * SLAB + BB * CC;  // 8256
constexpr int NSLAB_SM = 32;

typedef __attribute__((ext_vector_type(4))) short short4v;
typedef __attribute__((ext_vector_type(8))) short short8v;
typedef __attribute__((ext_vector_type(16))) float f32x16;
typedef __attribute__((ext_vector_type(4))) unsigned short us4;

union ABfrag { short8v v; short4v h[2]; };

__device__ __forceinline__ unsigned short f2bf(float f) {
  unsigned u = __float_as_uint(f);
  u += 0x7fffu + ((u >> 16) & 1u);  // RNE
  return (unsigned short)(u >> 16);
}

// One block per capsule i. 4 waves; wave w owns c = 4w..4w+3.
// Votes via v_mfma_f32_32x32x16_bf16: M=32 (2 batches x 16 rows), N=32 (l-half), K=16 (=P).
// A: m=lane&31, k=8*(lane>>5)+j ; B: n=lane&31, k=8*(lane>>5)+j
// C/D: col=lane&31, row=(reg&3)+8*(reg>>2)+4*(lane>>5)   [m74/m101 verified]
template <int PASS, int STORE>
__global__ __launch_bounds__(256, 2) void em_sweep(
    const float* __restrict__ x, const float* __restrict__ W,
    const float* __restrict__ mu, const float* __restrict__ T,
    float* __restrict__ Spart, int nslab) {
  const int i = blockIdx.x, t = threadIdx.x;
  const int w = t >> 6, lane = t & 63;
  const int ln31 = lane & 31, h = lane >> 5;
  const int cbase = 4 * w;

  float* S1p = Spart + (size_t)(blockIdx.x % nslab) * SLABTOT;
  float* S2p = S1p + SLAB;
  float* Srp = S1p + 2 * SLAB;

  // pitch 20 ushorts (40B): frag ds_read_b64 banks = 10*lane mod 32 -> <=2-way (free)
  __shared__ unsigned short Wbf[1024][20];
  __shared__ unsigned short pbf[64][20];
  __shared__ float act_s[64];
  __shared__ float T_s[64];
  __shared__ float sr_s[64];
  __shared__ float sc_s[64][17];
  __shared__ float rh2[16][64];

  // ---- stage W -> bf16 LDS (wave = one c-class, contiguous 4KB runs) ----
#pragma unroll
  for (int rep = 0; rep < 4; ++rep) {
    const int cl = rep * 256 + t;
    const int c = cl >> 6, l = cl & 63;
    const float* src = W + ((size_t)c * BC + i) * 1024 + l * 16;
#pragma unroll
    for (int q = 0; q < 4; ++q) {
      const float4 v = *reinterpret_cast<const float4*>(src + 4 * q);
      us4 u;
      u[0] = f2bf(v.x); u[1] = f2bf(v.y); u[2] = f2bf(v.z); u[3] = f2bf(v.w);
      *reinterpret_cast<us4*>(&Wbf[cl][4 * q]) = u;
    }
  }
  // ---- stage pose -> bf16 LDS, act -> f32 ----
  {
    const int b = t >> 6, p = (t >> 2) & 15, q = t & 3;
    const float4 v = *reinterpret_cast<const float4*>(
        x + ((size_t)(b * CH + p * BC + i)) * 16 + 4 * q);
    pbf[b * 16 + 4 * q + 0][p] = f2bf(v.x);
    pbf[b * 16 + 4 * q + 1][p] = f2bf(v.y);
    pbf[b * 16 + 4 * q + 2][p] = f2bf(v.z);
    pbf[b * 16 + 4 * q + 3][p] = f2bf(v.w);
  }
  if (t < 64) {
    const int b = t >> 4, xy = t & 15;
    act_s[t] = x[((size_t)(b * CH + PV * BC + i)) * 16 + xy];
    if (PASS == 1) { T_s[t] = T[t]; sr_s[t] = 0.f; }
  }

  float mur[4][2][4];  // [c_local][lh][b], per-lane l = lh*32 + ln31
  if (PASS == 1) {
#pragma unroll
    for (int cl_ = 0; cl_ < 4; ++cl_)
#pragma unroll
      for (int lh = 0; lh < 2; ++lh)
#pragma unroll
        for (int b = 0; b < 4; ++b)
          mur[cl_][lh][b] = mu[(b * CC + cbase + cl_) * LV + lh * 32 + ln31];
  }
  __syncthreads();

  const f32x16 zero16 = {};

  if (PASS == 1) {
    // ---- phase A: scores ----
#pragma unroll
    for (int pair = 0; pair < 2; ++pair) {
      ABfrag A;
      {
        const int r = pair * 32 + ln31;
        A.h[0] = *reinterpret_cast<const short4v*>(&pbf[r][8 * h]);
        A.h[1] = *reinterpret_cast<const short4v*>(&pbf[r][8 * h + 4]);
      }
#pragma unroll
      for (int cl_ = 0; cl_ < 4; ++cl_) {
        float scv[16];
#pragma unroll
        for (int j = 0; j < 16; ++j) scv[j] = 0.f;
#pragma unroll
        for (int lh = 0; lh < 2; ++lh) {
          ABfrag Bf;
          const int cl = (cbase + cl_) * 64 + lh * 32 + ln31;
          Bf.h[0] = *reinterpret_cast<const short4v*>(&Wbf[cl][8 * h]);
          Bf.h[1] = *reinterpret_cast<const short4v*>(&Wbf[cl][8 * h + 4]);
          const f32x16 acc =
              __builtin_amdgcn_mfma_f32_32x32x16_bf16(A.v, Bf.v, zero16, 0, 0, 0);
#pragma unroll
          for (int j = 0; j < 16; ++j) {
            const float d = acc[j] - mur[cl_][lh][pair * 2 + (j >> 3)];
            scv[j] = fmaf(d, d, scv[j]);
          }
        }
#pragma unroll
        for (int j = 0; j < 16; ++j) {  // sum over 32 cols (within half-wave)
          float v = scv[j];
          v += __shfl_xor(v, 1, 64);  v += __shfl_xor(v, 2, 64);
          v += __shfl_xor(v, 4, 64);  v += __shfl_xor(v, 8, 64);
          v += __shfl_xor(v, 16, 64);
          if (ln31 == 0)
            sc_s[pair * 32 + (j & 3) + 8 * (j >> 2) + 4 * h][cbase + cl_] = v;
        }
      }
    }
    __syncthreads();
    // ---- softmax over c (all 256 threads, 4x redundant rows) ----
    {
      const int r = t & 63, cq = t >> 6, b = r >> 4;
      float s[16];
#pragma unroll
      for (int cc = 0; cc < 16; ++cc) s[cc] = T_s[b * CC + cc] - sc_s[r][cc];
      float m = s[0];
#pragma unroll
      for (int cc = 1; cc < 16; ++cc) m = fmaxf(m, s[cc]);
      float den = 0.f;
#pragma unroll
      for (int cc = 0; cc < 16; ++cc) { s[cc] = __expf(s[cc] - m); den += s[cc]; }
      const float a = act_s[r] / den;
#pragma unroll
      for (int k = 0; k < 4; ++k) {
        const int cc = 4 * cq + k;
        const float rh = fmaxf(s[cc] * a, 0.01f);
        rh2[cc][r] = rh;
        atomicAdd(&sr_s[b * CC + cc], rh);
      }
    }
    __syncthreads();
  }

  // ---- phase B: S1/S2 ----
#pragma unroll
  for (int pair = 0; pair < 2; ++pair) {
    ABfrag A;
    {
      const int r = pair * 32 + ln31;
      A.h[0] = *reinterpret_cast<const short4v*>(&pbf[r][8 * h]);
      A.h[1] = *reinterpret_cast<const short4v*>(&pbf[r][8 * h + 4]);
    }
    float p1[8][2] = {}, p2[8][2] = {};  // [tile8][batch-half]
#pragma unroll
    for (int cl_ = 0; cl_ < 4; ++cl_) {
      float rq[16];
      if (PASS == 1) {
#pragma unroll
        for (int g = 0; g < 4; ++g) {
          const float4 v = *reinterpret_cast<const float4*>(
              &rh2[cbase + cl_][pair * 32 + 8 * g + 4 * h]);
          rq[4 * g + 0] = v.x; rq[4 * g + 1] = v.y;
          rq[4 * g + 2] = v.z; rq[4 * g + 3] = v.w;
        }
      } else {
#pragma unroll
        for (int g = 0; g < 4; ++g) {
          const float4 v = *reinterpret_cast<const float4*>(
              &act_s[pair * 32 + 8 * g + 4 * h]);
          rq[4 * g + 0] = fmaxf(v.x * 0.0625f, 0.01f);
          rq[4 * g + 1] = fmaxf(v.y * 0.0625f, 0.01f);
          rq[4 * g + 2] = fmaxf(v.z * 0.0625f, 0.01f);
          rq[4 * g + 3] = fmaxf(v.w * 0.0625f, 0.01f);
        }
      }
#pragma unroll
      for (int lh = 0; lh < 2; ++lh) {
        ABfrag Bf;
        const int cl = (cbase + cl_) * 64 + lh * 32 + ln31;
        Bf.h[0] = *reinterpret_cast<const short4v*>(&Wbf[cl][8 * h]);
        Bf.h[1] = *reinterpret_cast<const short4v*>(&Wbf[cl][8 * h + 4]);
        const f32x16 acc =
            __builtin_amdgcn_mfma_f32_32x32x16_bf16(A.v, Bf.v, zero16, 0, 0, 0);
        const int t8 = cl_ * 2 + lh;
#pragma unroll
        for (int j = 0; j < 16; ++j) {
          const float v = acc[j];
          const float rv = rq[j] * v;
          p1[t8][j >> 3] += rv;
          p2[t8][j >> 3] = fmaf(rv, v, p2[t8][j >> 3]);
        }
      }
    }
#pragma unroll
    for (int t8 = 0; t8 < 8; ++t8)
#pragma unroll
      for (int bh = 0; bh < 2; ++bh) {
        float v1 = p1[t8][bh]; v1 += __shfl_xor(v1, 32, 64);
        float v2 = p2[t8][bh]; v2 += __shfl_xor(v2, 32, 64);
        const int b = pair * 2 + bh, c = cbase + (t8 >> 1);
        const int idx = (b * CC + c) * LV + (t8 & 1) * 32 + ln31;
        if (STORE) {
          if (h == 0) { S1p[idx] = v1; S2p[idx] = v2; }
        } else if (h == 0) {
          atomicAdd(&S1p[idx], v1); atomicAdd(&S2p[idx], v2);
        }
      }
  }

  // ---- Sr ----
  if (PASS == 1) {
    if (t < 64) { if (STORE) Srp[t] = sr_s[t]; else atomicAdd(&Srp[t], sr_s[t]); }
  } else {
    if (t < 64) {
      const int b = t >> 4;
      float s = 0.f;
#pragma unroll
      for (int xy = 0; xy < 16; ++xy) s += fmaxf(act_s[b * 16 + xy] * 0.0625f, 0.01f);
      if (STORE) Srp[t] = s; else atomicAdd(&Srp[t], s);
    }
  }
}

__global__ void reduce_slabs(const float* __restrict__ Spart, float* __restrict__ Sred,
                             int nslab, int chunk) {
  const int idx = blockIdx.x * 256 + threadIdx.x;
  if (idx >= SLABTOT) return;
  const int s0 = blockIdx.y * chunk;
  const int s1 = min(s0 + chunk, nslab);
  float a = 0.f;
#pragma unroll 8
  for (int s = s0; s < s1; s++) a += Spart[(size_t)s * SLABTOT + idx];
  atomicAdd(&Sred[idx], a);
}

template <int FINAL>
__global__ void stats_post(const float* __restrict__ Sred,
                           const float* __restrict__ beta_v,
                           const float* __restrict__ beta_a,
                           const float* __restrict__ lam,
                           float* __restrict__ mu_out, float* __restrict__ T_out,
                           float* __restrict__ out) {
  const int t = threadIdx.x;
  if (t >= 64) return;
  const int b = t >> 4, c = t & 15;
  const float* S1 = Sred;
  const float* S2 = Sred + SLAB;
  const float sr = Sred[2 * SLAB + b * CC + c];
  const float inv = 1.f / sr;
  const float bv = beta_v[0];
  float csum = 0.f, lsum = 0.f;
  for (int l = 0; l < LV; l++) {
    const int idx = (b * CC + c) * LV + l;
    const float m = S1[idx] * inv;
    float s2 = S2[idx] * inv - m * m;
    s2 = fmaxf(s2, 0.01f);
    const float ls = logf(s2);
    csum += bv + ls;
    lsum += ls;
    if (FINAL) out[(size_t)b * 1040 + c * LV + l] = m;
    else mu_out[idx] = m;
  }
  const float z = lam[0] * (beta_a[c] - csum * sr);
  const float ac = 1.f / (1.f + expf(-z));
  if (FINAL) out[(size_t)b * 1040 + 1024 + c] = ac;
  else T_out[b * CC + c] = logf(ac) - 0.5f * (64.f * LOG_2PI_F + lsum);
}

extern "C" void kernel_launch(void* const* d_in, const int* in_sizes, int n_in,
                              void* d_out, int out_size, void* d_ws, size_t ws_size,
                              hipStream_t stream) {
  const float* x = (const float*)d_in[0];
  const float* W = (const float*)d_in[1];
  const float* beta_v = (const float*)d_in[2];
  const float* beta_a = (const float*)d_in[3];
  const float* lam = (const float*)d_in[4];
  float* out = (float*)d_out;

  const size_t need = ((size_t)BC * SLABTOT + SLABTOT + SLAB + 64) * sizeof(float);
  const int nslab = (ws_size >= need) ? BC : NSLAB_SM;
  const bool store = (nslab == BC);

  float* Spart = (float*)d_ws;
  float* Sred = Spart + (size_t)nslab * SLABTOT;
  float* muW = Sred + SLABTOT;
  float* Tw = muW + SLAB;

  const int chunk = 32;
  const dim3 rgrid((SLABTOT + 255) / 256, (nslab + chunk - 1) / chunk);

  // ---- pass 0 ----
  if (!store) hipMemsetAsync(Spart, 0, (size_t)nslab * SLABTOT * sizeof(float), stream);
  hipMemsetAsync(Sred, 0, SLABTOT * sizeof(float), stream);
  if (store) em_sweep<0, 1><<<dim3(BC), dim3(256), 0, stream>>>(x, W, nullptr, nullptr, Spart, nslab);
  else       em_sweep<0, 0><<<dim3(BC), dim3(256), 0, stream>>>(x, W, nullptr, nullptr, Spart, nslab);
  reduce_slabs<<<rgrid, dim3(256), 0, stream>>>(Spart, Sred, nslab, chunk);
  stats_post<0><<<dim3(1), dim3(64), 0, stream>>>(Sred, beta_v, beta_a, lam, muW, Tw, nullptr);

  // ---- pass 1 ----
  if (!store) hipMemsetAsync(Spart, 0, (size_t)nslab * SLABTOT * sizeof(float), stream);
  hipMemsetAsync(Sred, 0, SLABTOT * sizeof(float), stream);
  if (store) em_sweep<1, 1><<<dim3(BC), dim3(256), 0, stream>>>(x, W, muW, Tw, Spart, nslab);
  else       em_sweep<1, 0><<<dim3(BC), dim3(256), 0, stream>>>(x, W, muW, Tw, Spart, nslab);
  reduce_slabs<<<rgrid, dim3(256), 0, stream>>>(Spart, Sred, nslab, chunk);
  stats_post<1><<<dim3(1), dim3(64), 0, stream>>>(Sred, beta_v, beta_a, lam, nullptr, nullptr, out);
}